// Round 1
// baseline (379.485 us; speedup 1.0000x reference)
//
#include <hip/hip_runtime.h>

// MaskedAttention: performer-style relu-feature attention with RPE mask.
// Shapes: q/k/v [B,L,H,D], proj [M,D], mask [H,L,L], out [B,L,H,D], fp32.
// Restructured: out[b,i,h,:] = (sum_j mask[h,i,j]*(q'[i].k'[j]) * v[j,:]) / (q'[i].ks_sum[b,h,:])
// with ks_sum[b,h,m] = sum_j cmask[h,j]*k'[b,j,h,m], cmask[h,j] = sum_i mask[h,i,j].

#define B_ 16
#define L_ 576
#define H_ 12
#define D_ 64
#define M_ 8

__device__ __constant__ const float kRatio = 0.35355339059327373f; // 1/sqrt(M)
#define NUM_STAB 1e-3f

// ---------------- kernel 1: cmask[h][j] = sum_i mask[h][i][j] ----------------
__global__ void cmask_kernel(const float* __restrict__ mask, float* __restrict__ cmask) {
    int idx = blockIdx.x * 256 + threadIdx.x;
    if (idx >= H_ * L_) return;
    int h = idx / L_, j = idx % L_;
    const float* p = mask + (size_t)h * L_ * L_ + j;
    float s = 0.f;
#pragma unroll 4
    for (int i = 0; i < L_; ++i) s += p[(size_t)i * L_];
    cmask[idx] = s;
}

// ---------------- kernel 2: ks_sum[b][h][m] = sum_j cmask[h][j]*k'[b,j,h,m] ----------------
__global__ __launch_bounds__(256) void kssum_kernel(const float* __restrict__ key,
                                                    const float* __restrict__ proj,
                                                    const float* __restrict__ cmask,
                                                    float* __restrict__ ks_sum) {
    __shared__ float proj_s[M_ * D_];
    __shared__ float kbuf[32][68];  // pad 68 to spread banks
    const int h = blockIdx.x, b = blockIdx.y;
    const int t = threadIdx.x;
    proj_s[t] = proj[t];
    proj_s[t + 256] = proj[t + 256];
    const int jj = t & 31, m = t >> 5;
    float partial = 0.f;
    for (int jt = 0; jt < L_ / 32; ++jt) {
        __syncthreads();
#pragma unroll
        for (int p = 0; p < 2; ++p) {
            int idx = p * 256 + t;       // float4 index 0..511
            int row = idx >> 4, c4 = idx & 15;
            float4 val = *(const float4*)(key + (((size_t)b * L_ + jt * 32 + row) * H_ + h) * D_ + c4 * 4);
            float* dst = &kbuf[row][c4 * 4];
            dst[0] = val.x; dst[1] = val.y; dst[2] = val.z; dst[3] = val.w;
        }
        __syncthreads();
        float acc = 0.f;
#pragma unroll 8
        for (int kk = 0; kk < D_; ++kk) acc = fmaf(kbuf[jj][kk], proj_s[m * D_ + kk], acc);
        float kp = fmaxf(acc * kRatio, 0.f) + NUM_STAB;
        partial = fmaf(cmask[h * L_ + jt * 32 + jj], kp, partial);
    }
#pragma unroll
    for (int s = 16; s; s >>= 1) partial += __shfl_down(partial, s, 32);
    if (jj == 0) ks_sum[((size_t)b * H_ + h) * M_ + m] = partial;
}

// ---------------- kernel 3: main attention ----------------
// grid (L/64, H, B), block 256.
__global__ __launch_bounds__(256, 4) void attn_kernel(const float* __restrict__ q,
                                                      const float* __restrict__ k,
                                                      const float* __restrict__ v,
                                                      const float* __restrict__ proj,
                                                      const float* __restrict__ mask,
                                                      const float* __restrict__ ks_sum,
                                                      float* __restrict__ out) {
    constexpr int TI = 64, TJ = 32, NJT = L_ / TJ;  // 18 j-tiles
    __shared__ float proj_s[M_ * D_];   // 2 KB
    __shared__ float qp_s[TI][12];      // 3 KB   (row stride 12 floats = 48B, b128-aligned)
    __shared__ float kp_all[L_][M_];    // 18 KB  (row = 32B, b128-aligned)
    __shared__ float st[TJ][68];        // 8.7 KB (S^T tile; also Q/K staging buffer)
    __shared__ float vs[TJ][64];        // 8 KB
    __shared__ float kss[M_];

    const int t = threadIdx.x;
    const int it = blockIdx.x, h = blockIdx.y, b = blockIdx.z;
    const int i0 = it * TI;

    proj_s[t] = proj[t];
    proj_s[t + 256] = proj[t + 256];
    if (t < M_) kss[t] = ks_sum[((size_t)b * H_ + h) * M_ + t];

    const int jj = t & 31, mrow = t >> 5;  // feature-phase mapping: (row, m)

    // ---- Q' features for this i-tile (2 chunks of 32 rows) ----
    for (int c = 0; c < 2; ++c) {
        __syncthreads();
#pragma unroll
        for (int p = 0; p < 2; ++p) {
            int idx = p * 256 + t;
            int row = idx >> 4, c4 = idx & 15;
            float4 val = *(const float4*)(q + (((size_t)b * L_ + i0 + c * 32 + row) * H_ + h) * D_ + c4 * 4);
            float* dst = &st[row][c4 * 4];
            dst[0] = val.x; dst[1] = val.y; dst[2] = val.z; dst[3] = val.w;
        }
        __syncthreads();
        float acc = 0.f;
#pragma unroll 8
        for (int kk = 0; kk < D_; ++kk) acc = fmaf(st[jj][kk], proj_s[mrow * D_ + kk], acc);
        qp_s[c * 32 + jj][mrow] = fmaxf(acc * kRatio, 0.f) + NUM_STAB;
    }

    // ---- K' features for all of L (18 chunks of 32 rows) ----
    for (int c = 0; c < NJT; ++c) {
        __syncthreads();
#pragma unroll
        for (int p = 0; p < 2; ++p) {
            int idx = p * 256 + t;
            int row = idx >> 4, c4 = idx & 15;
            float4 val = *(const float4*)(k + (((size_t)b * L_ + c * 32 + row) * H_ + h) * D_ + c4 * 4);
            float* dst = &st[row][c4 * 4];
            dst[0] = val.x; dst[1] = val.y; dst[2] = val.z; dst[3] = val.w;
        }
        __syncthreads();
        float acc = 0.f;
#pragma unroll 8
        for (int kk = 0; kk < D_; ++kk) acc = fmaf(st[jj][kk], proj_s[mrow * D_ + kk], acc);
        kp_all[c * 32 + jj][mrow] = fmaxf(acc * kRatio, 0.f) + NUM_STAB;
    }

    // ---- main loop over j-tiles ----
    const int td = t & 15, ti = t >> 4;  // (d-group, i-group); thread owns i=ti*4..+3, d=td*4..+3
    float acc[4][4] = {{0.f}};
    const float* maskbase = mask + (size_t)h * L_ * L_;

    for (int jt = 0; jt < NJT; ++jt) {
        const int j0 = jt * TJ;
        __syncthreads();  // prev phase B done reading st/vs
        // stage V tile [32][64]
#pragma unroll
        for (int p = 0; p < 2; ++p) {
            int idx = p * 256 + t;
            int row = idx >> 4, c4 = idx & 15;
            float4 val = *(const float4*)(v + (((size_t)b * L_ + j0 + row) * H_ + h) * D_ + c4 * 4);
            *(float4*)&vs[row][c4 * 4] = val;
        }
        // this thread's K' column (j = j0+jj), held in regs
        float4 ka = *(const float4*)&kp_all[j0 + jj][0];
        float4 kb = *(const float4*)&kp_all[j0 + jj][4];
        // phase A: S^T[jj][i] = mask[h,i0+i,j0+jj] * (q'[i] . k'[j0+jj])
        float mv[8];
#pragma unroll
        for (int p = 0; p < 8; ++p) {
            int i = mrow + 8 * p;
            mv[p] = maskbase[(size_t)(i0 + i) * L_ + j0 + jj];
        }
#pragma unroll
        for (int p = 0; p < 8; ++p) {
            int i = mrow + 8 * p;
            float4 qa = *(const float4*)&qp_s[i][0];
            float4 qb = *(const float4*)&qp_s[i][4];
            float s = qa.x * ka.x + qa.y * ka.y + qa.z * ka.z + qa.w * ka.w +
                      qb.x * kb.x + qb.y * kb.y + qb.z * kb.z + qb.w * kb.w;
            st[jj][i] = s * mv[p];
        }
        __syncthreads();
        // phase B: acc[i][d] += S^T[j][i] * V[j][d]
#pragma unroll 4
        for (int j = 0; j < TJ; ++j) {
            float4 sv = *(const float4*)&st[j][ti * 4];
            float4 vv = *(const float4*)&vs[j][td * 4];
            float sr[4] = {sv.x, sv.y, sv.z, sv.w};
            float vr[4] = {vv.x, vv.y, vv.z, vv.w};
#pragma unroll
            for (int r = 0; r < 4; ++r)
#pragma unroll
                for (int c = 0; c < 4; ++c) acc[r][c] = fmaf(sr[r], vr[c], acc[r][c]);
        }
    }

    // ---- epilogue: divide by normalizer, store ----
#pragma unroll
    for (int r = 0; r < 4; ++r) {
        int i = ti * 4 + r;
        float4 qa = *(const float4*)&qp_s[i][0];
        float4 qb = *(const float4*)&qp_s[i][4];
        float norm = qa.x * kss[0] + qa.y * kss[1] + qa.z * kss[2] + qa.w * kss[3] +
                     qb.x * kss[4] + qb.y * kss[5] + qb.z * kss[6] + qb.w * kss[7];
        float inv = 1.0f / norm;
        float4 o;
        o.x = acc[r][0] * inv;
        o.y = acc[r][1] * inv;
        o.z = acc[r][2] * inv;
        o.w = acc[r][3] * inv;
        *(float4*)(out + (((size_t)b * L_ + i0 + i) * H_ + h) * D_ + td * 4) = o;
    }
}

extern "C" void kernel_launch(void* const* d_in, const int* in_sizes, int n_in,
                              void* d_out, int out_size, void* d_ws, size_t ws_size,
                              hipStream_t stream) {
    const float* q    = (const float*)d_in[0];
    const float* k    = (const float*)d_in[1];
    const float* v    = (const float*)d_in[2];
    const float* proj = (const float*)d_in[3];
    const float* mask = (const float*)d_in[4];
    float* out = (float*)d_out;

    float* ws = (float*)d_ws;
    float* cmask  = ws;                 // H*L floats
    float* ks_sum = ws + (size_t)H_ * L_;  // B*H*M floats

    cmask_kernel<<<(H_ * L_ + 255) / 256, 256, 0, stream>>>(mask, cmask);
    kssum_kernel<<<dim3(H_, B_), 256, 0, stream>>>(k, proj, cmask, ks_sum);
    attn_kernel<<<dim3(L_ / 64, H_, B_), 256, 0, stream>>>(q, k, v, proj, mask, ks_sum, out);
}

// Round 2
// 272.652 us; speedup vs baseline: 1.3918x; 1.3918x over previous
//
#include <hip/hip_runtime.h>

// MaskedAttention: performer-style relu-feature attention with RPE mask.
// out[b,i,h,:] = (sum_j mask[h,i,j]*(q'[i].k'[j]) * v[j,:]) / (q'[i].ks_sum[b,h,:])
// ks_sum[b,h,m] = sum_j cmask[h,j]*k'[b,j,h,m], cmask[h,j] = sum_i mask[h,i,j].
// Pipeline: zero -> cmask(atomic col-sums) -> feat(q',k' precompute) -> kssum -> attn.

#define B_ 16
#define L_ 576
#define H_ 12
#define D_ 64
#define M_ 8
#define NUM_STAB 1e-3f
#define RATIO 0.35355339059327373f  // 1/sqrt(M)

// ws layout (floats)
#define WS_CMASK 0                          // H*L       = 6912
#define WS_KSSUM (H_ * L_)                  // B*H*M     = 1536
#define WS_QP    (WS_KSSUM + B_ * H_ * M_)  // B*H*L*M   = 884736
#define WS_KP    (WS_QP + B_ * H_ * L_ * M_)

// ---------------- kernel 0: zero cmask ----------------
__global__ void zero_cmask(float* __restrict__ c) {
    c[blockIdx.x * 256 + threadIdx.x] = 0.f;  // grid 27 * 256 = 6912 exact
}

// ---------------- kernel 1: cmask[h][j] = sum_i mask[h][i][j] ----------------
// grid (H, 36): each block sums 16 rows, coalesced, atomicAdd partials.
__global__ __launch_bounds__(256) void cmask_kernel(const float* __restrict__ mask,
                                                    float* __restrict__ cmask) {
    const int h = blockIdx.x, ic = blockIdx.y, t = threadIdx.x;
    const float* base = mask + (size_t)h * L_ * L_ + (size_t)ic * 16 * L_;
    float a0 = 0.f, a1 = 0.f, a2 = 0.f;
#pragma unroll 4
    for (int r = 0; r < 16; ++r) {
        const float* p = base + (size_t)r * L_;
        a0 += p[t];
        a1 += p[t + 256];
        if (t < 64) a2 += p[t + 512];
    }
    float* c = cmask + h * L_;
    atomicAdd(&c[t], a0);
    atomicAdd(&c[t + 256], a1);
    if (t < 64) atomicAdd(&c[t + 512], a2);
}

// ---------------- kernel 2: features q',k' -> ws ([B,H,L,M] layout) ----------------
// grid (L/32, H, B), block 256.
__global__ __launch_bounds__(256) void feat_kernel(const float* __restrict__ q,
                                                   const float* __restrict__ k,
                                                   const float* __restrict__ proj,
                                                   float* __restrict__ qp,
                                                   float* __restrict__ kp) {
    __shared__ float proj_t[64][8];   // transposed + pre-scaled by RATIO
    __shared__ float xbuf[32][68];
    const int lc = blockIdx.x, h = blockIdx.y, b = blockIdx.z, t = threadIdx.x;
    {
        int m = t >> 6, kk = t & 63;
        proj_t[kk][m] = RATIO * proj[t];
        int t2 = t + 256;
        m = t2 >> 6; kk = t2 & 63;
        proj_t[kk][m] = RATIO * proj[t2];
    }
    const int row8 = t >> 3, m8 = t & 7;
#pragma unroll
    for (int s = 0; s < 2; ++s) {
        const float* src = (s == 0) ? q : k;
        float* dst = (s == 0) ? qp : kp;
        __syncthreads();
#pragma unroll
        for (int p = 0; p < 2; ++p) {
            int idx = p * 256 + t, row = idx >> 4, c4 = idx & 15;
            float4 val = *(const float4*)(src + (((size_t)b * L_ + lc * 32 + row) * H_ + h) * D_ + c4 * 4);
            *(float4*)&xbuf[row][c4 * 4] = val;
        }
        __syncthreads();
        float acc = 0.f;
#pragma unroll 8
        for (int kk = 0; kk < D_; ++kk) acc = fmaf(xbuf[row8][kk], proj_t[kk][m8], acc);
        dst[((size_t)(b * H_ + h) * L_ + lc * 32 + row8) * M_ + m8] = fmaxf(acc, 0.f) + NUM_STAB;
    }
}

// ---------------- kernel 3: ks_sum[b][h][m] = sum_j cmask[h][j]*k'[j][m] ----------------
__global__ __launch_bounds__(256) void kssum_kernel(const float* __restrict__ kp,
                                                    const float* __restrict__ cmask,
                                                    float* __restrict__ ks) {
    __shared__ float part[32][9];
    const int h = blockIdx.x, b = blockIdx.y, t = threadIdx.x;
    const int m = t & 7, jg = t >> 3;
    const float* kpb = kp + (size_t)(b * H_ + h) * L_ * M_;
    const float* cm = cmask + h * L_;
    float acc = 0.f;
#pragma unroll 2
    for (int it = 0; it < 18; ++it) {
        int j = it * 32 + jg;
        acc = fmaf(cm[j], kpb[(size_t)j * M_ + m], acc);
    }
    part[jg][m] = acc;
    __syncthreads();
    if (t < 8) {
        float s = 0.f;
#pragma unroll
        for (int g = 0; g < 32; ++g) s += part[g][t];
        ks[(b * H_ + h) * M_ + t] = s;
    }
}

// ---------------- kernel 4: main attention ----------------
// 1D grid 1728, XCD-swizzled: id = ((h*9+it)*2 + (b&1))*8 + (b>>1)
// Block: 256 threads, TI=64 x D=64 outputs. Wave w owns j = w*8..w*8+7 of each
// 32-j tile (split-j), 8x8 register tile per thread, combined via LDS at end.
__global__ __launch_bounds__(256, 4) void attn_kernel(const float* __restrict__ v,
                                                      const float* __restrict__ mask,
                                                      const float* __restrict__ qp,
                                                      const float* __restrict__ kp,
                                                      const float* __restrict__ ks,
                                                      float* __restrict__ out) {
    // pool: st[j][i] = pool[j*68+i] (j<32); vs[j][d] = pool[2176+j*64+d]; cbuf[i][d] = pool[i*68+d]
    __shared__ float pool[64 * 68];   // 17408 B
    __shared__ float qp_s[64][12];    // 3072 B (stride 48B keeps b128 alignment)
    __shared__ float kss[8];

    const int t = threadIdx.x;
    int id = blockIdx.x;
    const int bhi = id & 7;  id >>= 3;
    const int blo = id & 1;  id >>= 1;
    const int it = id % 9, h = id / 9;
    const int b = bhi * 2 + blo;
    const int i0 = it * 64;

    // preamble: load q' tile + ks_sum
    {
        const float* qpb = qp + ((size_t)(b * H_ + h) * L_ + i0) * M_;
        int row = t >> 3, m = t & 7;
        qp_s[row][m] = qpb[t];
        int t2 = t + 256;
        row = t2 >> 3; m = t2 & 7;
        qp_s[row][m] = qpb[t2];
        if (t < 8) kss[t] = ks[(b * H_ + h) * M_ + t];
    }

    const int jj = t & 31, mrow = t >> 5;       // phase-A mapping
    const int wv = t >> 6, l = t & 63;          // phase-B mapping
    const int i0t = (l >> 3) * 8, d0t = (l & 7) * 8;
    const float* maskbase = mask + (size_t)h * L_ * L_;
    const float* kpb = kp + (size_t)(b * H_ + h) * L_ * M_;
    const float* vb = v + ((size_t)b * L_ * H_ + h) * D_;

    float acc[8][8] = {{0.f}};

    for (int jt = 0; jt < 18; ++jt) {
        const int j0 = jt * 32;
        __syncthreads();
        // stage V tile [32][64]
#pragma unroll
        for (int p = 0; p < 2; ++p) {
            int idx = p * 256 + t, row = idx >> 4, c4 = idx & 15;
            float4 val = *(const float4*)(vb + (size_t)(j0 + row) * H_ * D_ + c4 * 4);
            *(float4*)&pool[2176 + row * 64 + c4 * 4] = val;
        }
        // phase A: S^T[jj][i] = mask[h,i0+i,j0+jj] * (q'[i] . k'[j0+jj])
        {
            const float* kpp = kpb + (size_t)(j0 + jj) * M_;
            float4 ka = *(const float4*)kpp;
            float4 kb = *(const float4*)(kpp + 4);
            float mv[8];
#pragma unroll
            for (int p = 0; p < 8; ++p)
                mv[p] = maskbase[(size_t)(i0 + mrow + 8 * p) * L_ + j0 + jj];
#pragma unroll
            for (int p = 0; p < 8; ++p) {
                int i = mrow + 8 * p;
                float4 qa = *(const float4*)&qp_s[i][0];
                float4 qb = *(const float4*)&qp_s[i][4];
                float s = qa.x * ka.x + qa.y * ka.y + qa.z * ka.z + qa.w * ka.w +
                          qb.x * kb.x + qb.y * kb.y + qb.z * kb.z + qb.w * kb.w;
                pool[jj * 68 + i] = s * mv[p];
            }
        }
        __syncthreads();
        // phase B: wave wv handles j = wv*8 .. wv*8+7
#pragma unroll 2
        for (int jl = 0; jl < 8; ++jl) {
            int j = wv * 8 + jl;
            const float* sp = &pool[j * 68 + i0t];
            const float* vp = &pool[2176 + j * 64 + d0t];
            float4 s0 = *(const float4*)sp, s1 = *(const float4*)(sp + 4);
            float4 v0 = *(const float4*)vp, v1 = *(const float4*)(vp + 4);
            float sr[8] = {s0.x, s0.y, s0.z, s0.w, s1.x, s1.y, s1.z, s1.w};
            float vr[8] = {v0.x, v0.y, v0.z, v0.w, v1.x, v1.y, v1.z, v1.w};
#pragma unroll
            for (int r = 0; r < 8; ++r)
#pragma unroll
                for (int c = 0; c < 8; ++c) acc[r][c] = fmaf(sr[r], vr[c], acc[r][c]);
        }
    }

    // combine 4 wave-partials into cbuf (serial over waves; 2-way banks = free)
    __syncthreads();
#pragma unroll 1
    for (int w = 0; w < 4; ++w) {
        if (wv == w) {
#pragma unroll
            for (int r = 0; r < 8; ++r) {
                float* cp = &pool[(i0t + r) * 68 + d0t];
                if (w == 0) {
                    *(float4*)cp = make_float4(acc[r][0], acc[r][1], acc[r][2], acc[r][3]);
                    *(float4*)(cp + 4) = make_float4(acc[r][4], acc[r][5], acc[r][6], acc[r][7]);
                } else {
                    float4 c0 = *(const float4*)cp, c1 = *(const float4*)(cp + 4);
                    c0.x += acc[r][0]; c0.y += acc[r][1]; c0.z += acc[r][2]; c0.w += acc[r][3];
                    c1.x += acc[r][4]; c1.y += acc[r][5]; c1.z += acc[r][6]; c1.w += acc[r][7];
                    *(float4*)cp = c0;
                    *(float4*)(cp + 4) = c1;
                }
            }
        }
        __syncthreads();
    }

    // epilogue: normalize and store
    const int td = t & 15, tig = t >> 4;
#pragma unroll
    for (int r = 0; r < 4; ++r) {
        int i = tig * 4 + r;
        float4 qa = *(const float4*)&qp_s[i][0];
        float4 qb = *(const float4*)&qp_s[i][4];
        float norm = qa.x * kss[0] + qa.y * kss[1] + qa.z * kss[2] + qa.w * kss[3] +
                     qb.x * kss[4] + qb.y * kss[5] + qb.z * kss[6] + qb.w * kss[7];
        float inv = 1.0f / norm;
        const float* cp = &pool[i * 68 + td * 4];
        float4 o;
        o.x = cp[0] * inv; o.y = cp[1] * inv; o.z = cp[2] * inv; o.w = cp[3] * inv;
        *(float4*)(out + (((size_t)b * L_ + i0 + i) * H_ + h) * D_ + td * 4) = o;
    }
}

extern "C" void kernel_launch(void* const* d_in, const int* in_sizes, int n_in,
                              void* d_out, int out_size, void* d_ws, size_t ws_size,
                              hipStream_t stream) {
    const float* q    = (const float*)d_in[0];
    const float* k    = (const float*)d_in[1];
    const float* v    = (const float*)d_in[2];
    const float* proj = (const float*)d_in[3];
    const float* mask = (const float*)d_in[4];
    float* out = (float*)d_out;

    float* ws = (float*)d_ws;
    float* cmask = ws + WS_CMASK;
    float* ks    = ws + WS_KSSUM;
    float* qp_w  = ws + WS_QP;
    float* kp_w  = ws + WS_KP;

    zero_cmask<<<27, 256, 0, stream>>>(cmask);
    cmask_kernel<<<dim3(H_, 36), 256, 0, stream>>>(mask, cmask);
    feat_kernel<<<dim3(L_ / 32, H_, B_), 256, 0, stream>>>(q, k, proj, qp_w, kp_w);
    kssum_kernel<<<dim3(H_, B_), 256, 0, stream>>>(kp_w, cmask, ks);
    attn_kernel<<<1728, 256, 0, stream>>>(v, mask, qp_w, kp_w, ks, out);
}

// Round 3
// 202.782 us; speedup vs baseline: 1.8714x; 1.3446x over previous
//
#include <hip/hip_runtime.h>

// MaskedAttention: performer-style relu-feature attention with RPE mask.
// out[b,i,h,:] = (sum_j mask[h,i,j]*(q'[i].k'[j]) * v[j,:]) / (sum_j cmask[h,j]*(q'[i].k'[j]))
// cmask[h,j] = sum_i mask[h,i,j].
// Pipeline: feat_cmask (q',k' features + mask col-sums) -> attn (MFMA split-bf16).

#define B_ 16
#define L_ 576
#define H_ 12
#define D_ 64
#define M_ 8
#define NUM_STAB 1e-3f
#define RATIO 0.35355339059327373f  // 1/sqrt(M)

typedef __attribute__((ext_vector_type(8))) short short8;
typedef __attribute__((ext_vector_type(4))) float f32x4;

__device__ inline unsigned short f2bf(float x) {  // RNE fp32 -> bf16 bits
    union { float f; unsigned u; } a; a.f = x;
    unsigned r = (a.u + 0x7FFFu + ((a.u >> 16) & 1u)) >> 16;
    return (unsigned short)r;
}
__device__ inline float bf2f(unsigned short h) {
    union { float f; unsigned u; } a; a.u = ((unsigned)h) << 16;
    return a.f;
}

// ws layout (floats)
#define WS_CMASK 0                      // H*L = 6912
#define WS_QP    (H_ * L_)              // B*H*L*M = 884736
#define WS_KP    (WS_QP + B_ * H_ * L_ * M_)

// ---------------- kernel 1: features q',k' -> ws + fused cmask col-sums ----------------
// grid (L/32, H, B), block 256. Blocks with b<2 additionally compute
// cmask[h, lc*32 + b*16 .. +16) = sum_i mask[h,i,col] (no atomics needed).
__global__ __launch_bounds__(256) void feat_cmask_kernel(const float* __restrict__ q,
                                                         const float* __restrict__ k,
                                                         const float* __restrict__ proj,
                                                         const float* __restrict__ mask,
                                                         float* __restrict__ qp,
                                                         float* __restrict__ kp,
                                                         float* __restrict__ cmask) {
    __shared__ float proj_t[64][8];   // transposed + pre-scaled by RATIO
    __shared__ float xbuf[32][68];
    const int lc = blockIdx.x, h = blockIdx.y, b = blockIdx.z, t = threadIdx.x;
    {
        int m = t >> 6, kk = t & 63;
        proj_t[kk][m] = RATIO * proj[t];
        int t2 = t + 256;
        m = t2 >> 6; kk = t2 & 63;
        proj_t[kk][m] = RATIO * proj[t2];
    }
    const int row8 = t >> 3, m8 = t & 7;
#pragma unroll
    for (int s = 0; s < 2; ++s) {
        const float* src = (s == 0) ? q : k;
        float* dst = (s == 0) ? qp : kp;
        __syncthreads();
#pragma unroll
        for (int p = 0; p < 2; ++p) {
            int idx = p * 256 + t, row = idx >> 4, c4 = idx & 15;
            float4 val = *(const float4*)(src + (((size_t)b * L_ + lc * 32 + row) * H_ + h) * D_ + c4 * 4);
            *(float4*)&xbuf[row][c4 * 4] = val;
        }
        __syncthreads();
        float acc = 0.f;
#pragma unroll 8
        for (int kk = 0; kk < D_; ++kk) acc = fmaf(xbuf[row8][kk], proj_t[kk][m8], acc);
        dst[((size_t)(b * H_ + h) * L_ + lc * 32 + row8) * M_ + m8] = fmaxf(acc, 0.f) + NUM_STAB;
    }
    // fused cmask: blocks b<2 sum 16 columns each over all 576 rows
    if (b < 2) {
        const int c = t & 15, r16 = t >> 4;
        const int col0 = lc * 32 + b * 16;
        const float* mb = mask + (size_t)h * L_ * L_ + col0 + c;
        float a = 0.f;
#pragma unroll 4
        for (int k2 = 0; k2 < 36; ++k2) a += mb[(size_t)(r16 + 16 * k2) * L_];
        __syncthreads();  // xbuf free after feature phase
        float* red = &xbuf[0][0];
        red[c * 16 + r16] = a;
        __syncthreads();
        if (t < 16) {
            float s = 0.f;
#pragma unroll
            for (int g = 0; g < 16; ++g) s += red[t * 16 + g];
            cmask[h * L_ + col0 + t] = s;
        }
    }
}

// ---------------- kernel 2: main attention (MFMA, split-bf16 exact) ----------------
// grid 1728 (9 it x 12 h x 16 b, XCD-swizzled), block 256.
// Per block: 64 i-rows x 64 d-cols. jt loop: 18 tiles of 32 j.
// Phase A: S_raw = Q'.K'^T via 16x16x32 bf16 MFMA, limbs packed in K
//          (A = [Qh|Ql|0|0], B1 = [Kh;Kl;0;0], B2 = [Kl;Kh;0;0] -> exact fp32 product).
// Phase B: O += S.V, Sp = [Sh|Sl] (64 kslots), Bt = [Vh|Vl]; 4 MFMAs/sub-tile via chunk swap.
// Normalizer accumulated inline from raw S in C-layout; shfl_xor reduce over j-lanes.
__global__ __launch_bounds__(256, 4) void attn_kernel(const float* __restrict__ v,
                                                      const float* __restrict__ mask,
                                                      const float* __restrict__ qp,
                                                      const float* __restrict__ kp,
                                                      const float* __restrict__ cmask,
                                                      float* __restrict__ out) {
    __shared__ __align__(16) unsigned short Sp[64 * 72];  // [i][kslot] Sh:0-31 Sl:32-63 pad:64-71
    __shared__ __align__(16) unsigned short Bt[64 * 72];  // [d][kslot] Vh:0-31 Vl:32-63
    __shared__ __align__(16) unsigned short Qp[64 * 32];  // [i][kslot] Qh:0-7 Ql:8-15 zero:16-31
    __shared__ __align__(16) unsigned short Kp[32 * 32];  // [j][kslot] Kh:0-7 Kl:8-15 zero:16-31
    __shared__ float cm_s[L_];

    const int t = threadIdx.x;
    int id = blockIdx.x;
    const int bhi = id & 7; id >>= 3;
    const int blo = id & 1; id >>= 1;
    const int it = id % 9, h = id / 9;
    const int b = bhi * 2 + blo;
    const int i0 = it * 64;

    const float* maskbase = mask + (size_t)h * L_ * L_;
    const float* kpb = kp + (size_t)(b * H_ + h) * L_ * M_;
    const float* qpb = qp + ((size_t)(b * H_ + h) * L_ + i0) * M_;
    const float* vb  = v + ((size_t)b * L_ * H_ + h) * D_;

    // stage cmask row for this head
    cm_s[t] = cmask[h * L_ + t];
    cm_s[t + 256] = cmask[h * L_ + t + 256];
    if (t < 64) cm_s[t + 512] = cmask[h * L_ + t + 512];

    // build Q' limbs (once)
    {
        int i = t & 63, p = t >> 6;
        float q0 = qpb[i * 8 + 2 * p], q1 = qpb[i * 8 + 2 * p + 1];
        unsigned short h0 = f2bf(q0), h1 = f2bf(q1);
        unsigned short l0 = f2bf(q0 - bf2f(h0)), l1 = f2bf(q1 - bf2f(h1));
        unsigned* qw = (unsigned*)Qp;
        qw[i * 16 + p]      = (unsigned)h0 | ((unsigned)h1 << 16);
        qw[i * 16 + 4 + p]  = (unsigned)l0 | ((unsigned)l1 << 16);
        qw[i * 16 + 8 + p]  = 0u;
        qw[i * 16 + 12 + p] = 0u;
    }
    // zero Kp pad cols 16..31 (once; staging only writes cols 0..15)
    {
        unsigned* kw = (unsigned*)Kp;
        int row = t >> 3, cp = t & 7;
        kw[row * 16 + 8 + cp] = 0u;
    }
    __syncthreads();

    const int lane = t & 63, wv = t >> 6;
    const int c15 = lane & 15, kq = lane >> 4;

    // loop-invariant A-frag for phase A: rows i = 16*wv + c15
    short8 afq = *(const short8*)&Qp[(16 * wv + c15) * 32 + kq * 8];

    f32x4 acc[4];
    acc[0] = (f32x4){0.f, 0.f, 0.f, 0.f};
    acc[1] = acc[0]; acc[2] = acc[0]; acc[3] = acc[0];
    float nacc[4] = {0.f, 0.f, 0.f, 0.f};

    const int dS = t & 63, jgS = t >> 6;  // V-staging mapping
    const int jK = t >> 3, mK = t & 7;    // Kp-staging mapping
    const int ko2 = (kq < 2) ? (8 - kq * 8) : kq * 8;  // variant-2 kslot base

    for (int jt = 0; jt < 18; ++jt) {
        const int j0 = jt * 32;
        __syncthreads();  // [B1] prior reads of Sp/Bt/Kp done
        // stage K' limbs
        {
            float kv = kpb[(j0 + jK) * 8 + mK];
            unsigned short kh = f2bf(kv);
            unsigned short kl = f2bf(kv - bf2f(kh));
            Kp[jK * 32 + mK] = kh;
            Kp[jK * 32 + 8 + mK] = kl;
        }
        // stage V limbs: thread owns column d, 8 j's
        {
            unsigned short vh[8], vl[8];
#pragma unroll
            for (int qv = 0; qv < 8; ++qv) {
                float vf = vb[(size_t)(j0 + 8 * jgS + qv) * H_ * D_ + dS];
                vh[qv] = f2bf(vf);
                vl[qv] = f2bf(vf - bf2f(vh[qv]));
            }
            *(short8*)&Bt[dS * 72 + 8 * jgS] = *(const short8*)vh;
            *(short8*)&Bt[dS * 72 + 32 + 8 * jgS] = *(const short8*)vl;
        }
        __syncthreads();  // [B2]
        // phase A: raw S via MFMA (exact split product)
        {
            f32x4 s2[2];
#pragma unroll
            for (int tj = 0; tj < 2; ++tj) {
                short8 b1 = *(const short8*)&Kp[(16 * tj + c15) * 32 + kq * 8];
                short8 b2 = *(const short8*)&Kp[(16 * tj + c15) * 32 + ko2];
                f32x4 z = (f32x4){0.f, 0.f, 0.f, 0.f};
                z = __builtin_amdgcn_mfma_f32_16x16x32_bf16(afq, b1, z, 0, 0, 0);
                z = __builtin_amdgcn_mfma_f32_16x16x32_bf16(afq, b2, z, 0, 0, 0);
                s2[tj] = z;
            }
            float mload[8];
#pragma unroll
            for (int tj = 0; tj < 2; ++tj)
#pragma unroll
                for (int r = 0; r < 4; ++r)
                    mload[tj * 4 + r] =
                        maskbase[(size_t)(i0 + 16 * wv + 4 * kq + r) * L_ + j0 + 16 * tj + c15];
            float cm0 = cm_s[j0 + c15], cm1 = cm_s[j0 + 16 + c15];
#pragma unroll
            for (int tj = 0; tj < 2; ++tj) {
                float cmv = tj ? cm1 : cm0;
#pragma unroll
                for (int r = 0; r < 4; ++r) {
                    float raw = s2[tj][r];
                    nacc[r] = fmaf(cmv, raw, nacc[r]);
                    float sm = raw * mload[tj * 4 + r];
                    unsigned short sh = f2bf(sm);
                    unsigned short sl = f2bf(sm - bf2f(sh));
                    int i = 16 * wv + 4 * kq + r;
                    Sp[i * 72 + 16 * tj + c15] = sh;
                    Sp[i * 72 + 32 + 16 * tj + c15] = sl;
                }
            }
        }
        __syncthreads();  // [B3]
        // phase B: O += S.V (4 MFMAs per d-subtile cover all limb cross terms)
        {
            short8 as0 = *(const short8*)&Sp[(16 * wv + c15) * 72 + kq * 8];
            short8 as1 = *(const short8*)&Sp[(16 * wv + c15) * 72 + 32 + kq * 8];
#pragma unroll
            for (int di = 0; di < 4; ++di) {
                const unsigned short* bp = &Bt[(16 * di + c15) * 72 + kq * 8];
                short8 bs0 = *(const short8*)bp;
                short8 bs1 = *(const short8*)(bp + 32);
                acc[di] = __builtin_amdgcn_mfma_f32_16x16x32_bf16(as0, bs0, acc[di], 0, 0, 0);
                acc[di] = __builtin_amdgcn_mfma_f32_16x16x32_bf16(as1, bs1, acc[di], 0, 0, 0);
                acc[di] = __builtin_amdgcn_mfma_f32_16x16x32_bf16(as0, bs1, acc[di], 0, 0, 0);
                acc[di] = __builtin_amdgcn_mfma_f32_16x16x32_bf16(as1, bs0, acc[di], 0, 0, 0);
            }
        }
    }

    // normalizer: reduce nacc over the 16 j-lanes (c15) of each kq-group
#pragma unroll
    for (int r = 0; r < 4; ++r) {
        float nv = nacc[r];
        nv += __shfl_xor(nv, 1);
        nv += __shfl_xor(nv, 2);
        nv += __shfl_xor(nv, 4);
        nv += __shfl_xor(nv, 8);
        nacc[r] = 1.0f / nv;
    }
    // epilogue: C-layout row = 16*wv + 4*kq + r, col = 16*di + c15
#pragma unroll
    for (int di = 0; di < 4; ++di)
#pragma unroll
        for (int r = 0; r < 4; ++r) {
            int i = 16 * wv + 4 * kq + r;
            out[(((size_t)b * L_ + i0 + i) * H_ + h) * D_ + 16 * di + c15] = acc[di][r] * nacc[r];
        }
}

extern "C" void kernel_launch(void* const* d_in, const int* in_sizes, int n_in,
                              void* d_out, int out_size, void* d_ws, size_t ws_size,
                              hipStream_t stream) {
    const float* q    = (const float*)d_in[0];
    const float* k    = (const float*)d_in[1];
    const float* v    = (const float*)d_in[2];
    const float* proj = (const float*)d_in[3];
    const float* mask = (const float*)d_in[4];
    float* out = (float*)d_out;

    float* ws = (float*)d_ws;
    float* cmask = ws + WS_CMASK;
    float* qp_w  = ws + WS_QP;
    float* kp_w  = ws + WS_KP;

    feat_cmask_kernel<<<dim3(L_ / 32, H_, B_), 256, 0, stream>>>(q, k, proj, mask, qp_w, kp_w, cmask);
    attn_kernel<<<1728, 256, 0, stream>>>(v, mask, qp_w, kp_w, cmask, out);
}

// Round 4
// 182.784 us; speedup vs baseline: 2.0761x; 1.1094x over previous
//
#include <hip/hip_runtime.h>

// MaskedAttention: performer-style relu-feature attention with RPE mask.
// out[b,i,h,:] = (sum_j mask[h,i,j]*(q'[i].k'[j]) * v[j,:]) / (sum_j cmask[h,j]*(q'[i].k'[j]))
// cmask[h,j] = sum_i mask[h,i,j].
// Round 4: pure-bf16 MFMA (error budget: outputs ~1e-3, denom ~6.6e6, 576-term
// random-sign sums -> absmax ~3e-6 << 1.39e-5 threshold). feat: shfl-butterfly,
// no LDS. attn: transposed phase A (S^T), wave-private Sp, 1 barrier/jt, reg prefetch.

#define B_ 16
#define L_ 576
#define H_ 12
#define D_ 64
#define M_ 8
#define NUM_STAB 1e-3f
#define RATIO 0.35355339059327373f  // 1/sqrt(M)

typedef __attribute__((ext_vector_type(8))) short short8;
typedef __attribute__((ext_vector_type(4))) float f32x4;

union Pack {
    uint4 u4;
    short8 s8;
    uint2 u2[2];
    unsigned u[4];
    unsigned short us[8];
};

__device__ inline unsigned short f2bf(float x) {  // RNE fp32 -> bf16 bits
    union { float f; unsigned u; } a; a.f = x;
    unsigned r = (a.u + 0x7FFFu + ((a.u >> 16) & 1u)) >> 16;
    return (unsigned short)r;
}

// ws layout: cmask H*L floats, then qp/kp as bf16 [B,H,L,M]
#define WS_QP_OFF (H_ * L_)              // in floats
#define QP_ELEMS  ((size_t)B_ * H_ * L_ * M_)

// ---------------- kernel 1: features (bf16 out) + fused cmask col-sums ----------------
// grid (L/32, H, B), block 256. No LDS in the feature path; proj in VGPRs.
__global__ __launch_bounds__(256) void feat_kernel(const float* __restrict__ q,
                                                   const float* __restrict__ k,
                                                   const float* __restrict__ proj,
                                                   const float* __restrict__ mask,
                                                   unsigned short* __restrict__ qp,
                                                   unsigned short* __restrict__ kp,
                                                   float* __restrict__ cmask) {
    __shared__ float cred[4][16];
    const int lc = blockIdx.x, h = blockIdx.y, b = blockIdx.z, t = threadIdx.x;
    const int wv = t >> 6, l = t & 63, r8 = l >> 3, c8 = l & 7;
    const int row = lc * 32 + wv * 8 + r8;

    float4 pj0[8], pj1[8];  // proj[m][c8*8 .. +7] in regs (64 VGPRs)
#pragma unroll
    for (int m = 0; m < 8; ++m) {
        pj0[m] = *(const float4*)(proj + m * 64 + c8 * 8);
        pj1[m] = *(const float4*)(proj + m * 64 + c8 * 8 + 4);
    }

#pragma unroll
    for (int s = 0; s < 2; ++s) {
        const float* src = s ? k : q;
        unsigned short* dst = s ? kp : qp;
        const float* xp = src + (((size_t)b * L_ + row) * H_ + h) * D_ + c8 * 8;
        float4 x0 = *(const float4*)xp;
        float4 x1 = *(const float4*)(xp + 4);
        x0.x *= RATIO; x0.y *= RATIO; x0.z *= RATIO; x0.w *= RATIO;
        x1.x *= RATIO; x1.y *= RATIO; x1.z *= RATIO; x1.w *= RATIO;
        float p[8];
#pragma unroll
        for (int m = 0; m < 8; ++m) {
            p[m] = x0.x * pj0[m].x + x0.y * pj0[m].y + x0.z * pj0[m].z + x0.w * pj0[m].w
                 + x1.x * pj1[m].x + x1.y * pj1[m].y + x1.z * pj1[m].z + x1.w * pj1[m].w;
        }
#pragma unroll
        for (int st = 1; st <= 4; st <<= 1) {
#pragma unroll
            for (int m = 0; m < 8; ++m) p[m] += __shfl_xor(p[m], st, 64);
        }
        float r = p[0];
        r = (c8 == 1) ? p[1] : r;
        r = (c8 == 2) ? p[2] : r;
        r = (c8 == 3) ? p[3] : r;
        r = (c8 == 4) ? p[4] : r;
        r = (c8 == 5) ? p[5] : r;
        r = (c8 == 6) ? p[6] : r;
        r = (c8 == 7) ? p[7] : r;
        r = fmaxf(r, 0.f) + NUM_STAB;
        dst[((size_t)(b * H_ + h) * L_ + row) * 8 + c8] = f2bf(r);
    }

    // fused cmask: blocks b<2 sum 16 columns each over all 576 rows
    if (b < 2) {
        const int c = t & 15, rg = t >> 4;
        const int col0 = lc * 32 + b * 16;
        const float* mb = mask + (size_t)h * L_ * L_ + col0 + c;
        float a = 0.f;
#pragma unroll 4
        for (int k2 = 0; k2 < 36; ++k2) a += mb[(size_t)(rg + 16 * k2) * L_];
        a += __shfl_xor(a, 16, 64);
        a += __shfl_xor(a, 32, 64);
        if ((l >> 4) == 0) cred[wv][c] = a;
        __syncthreads();
        if (t < 16) cmask[h * L_ + col0 + t] = cred[0][t] + cred[1][t] + cred[2][t] + cred[3][t];
    }
}

// ---------------- kernel 2: main attention (pure bf16 MFMA) ----------------
// grid 1728 (XCD-swizzled), block 256 (4 waves). Per block: 64 i x 64 d.
// Phase A (per wave, i-chunk 16*wv): S^T[j][i] = K'.Q'^T via 2 MFMAs (K slots 0..7 = m).
//   C-layout row = j-within-16 = 4*kq+r  -> 4 consecutive j per lane -> b64 S-store.
// Sp is wave-private (wave writes/reads only rows i=16wv..+15) -> no barrier needed for it.
// Phase B: O[i][d] += S[i][j].V[j][d], K=32 j-slots exact; Bt (V bf16) double-buffered,
// single __syncthreads per jt. V/mask/K' prefetched one tile ahead into registers.
__global__ __launch_bounds__(256, 4) void attn_kernel(const float* __restrict__ v,
                                                      const float* __restrict__ mask,
                                                      const unsigned short* __restrict__ qp,
                                                      const unsigned short* __restrict__ kp,
                                                      const float* __restrict__ cmask,
                                                      float* __restrict__ out) {
    __shared__ __align__(16) unsigned short Sp[4 * 16 * 40];   // per-wave [16 i][40 j-slots]
    __shared__ __align__(16) unsigned short Bt[2][64 * 40];    // [d][40 j-slots], dbuf
    __shared__ float cm_s[L_];

    const int t = threadIdx.x;
    int id = blockIdx.x;
    const int bhi = id & 7; id >>= 3;
    const int blo = id & 1; id >>= 1;
    const int it = id % 9, h = id / 9;
    const int b = bhi * 2 + blo;
    const int i0 = it * 64;

    const int wv = t >> 6, l = t & 63, c15 = l & 15, kq = l >> 4;

    cm_s[t] = cmask[h * L_ + t];
    cm_s[t + 256] = cmask[h * L_ + t + 256];
    if (t < 64) cm_s[t + 512] = cmask[h * L_ + t + 512];

    const float* maskbase = mask + (size_t)h * L_ * L_ + (size_t)(i0 + 16 * wv + c15) * L_;
    const unsigned short* kpb = kp + (size_t)(b * H_ + h) * L_ * 8;
    const float* vb = v + ((size_t)b * L_ * H_ + h) * D_ + l;

    // loop-invariant Q' B-fragment: lane (c15,kq=0) holds Q'[i0+16wv+c15][0..7]
    short8 Bq;
    {
        Pack pk; pk.u4 = make_uint4(0, 0, 0, 0);
        if (kq == 0) {
            const unsigned short* qpb = qp + ((size_t)(b * H_ + h) * L_ + i0 + 16 * wv + c15) * 8;
            pk.u4 = *(const uint4*)qpb;
        }
        Bq = pk.s8;
    }

    unsigned short* SpW = Sp + wv * 16 * 40;

    f32x4 acc0 = {0.f, 0.f, 0.f, 0.f}, acc1 = acc0, acc2 = acc0, acc3 = acc0;
    float nacc = 0.f;

    // prefetch tile 0: V column (8 j's), mask float4 x2, K' row (kq<2 lanes)
    float vf[8];
    float4 mv0, mv1;
    uint4 kraw = make_uint4(0, 0, 0, 0);
    {
#pragma unroll
        for (int qv = 0; qv < 8; ++qv) vf[qv] = vb[(size_t)(8 * wv + qv) * (H_ * D_)];
        mv0 = *(const float4*)(maskbase + 4 * kq);
        mv1 = *(const float4*)(maskbase + 16 + 4 * kq);
        if (kq < 2) kraw = *(const uint4*)(kpb + (size_t)(16 * kq + c15) * 8);
    }

    __syncthreads();  // cm_s ready

    for (int jt = 0; jt < 18; ++jt) {
        const int j0 = jt * 32;
        const int slab = jt & 1;

        // build K' A-fragments: A0 = tile j0..j0+15 (kq0 lanes), A1 = j0+16..+31
        Pack a0, a1;
        a1.u[0] = __shfl_down(kraw.x, 16, 64);
        a1.u[1] = __shfl_down(kraw.y, 16, 64);
        a1.u[2] = __shfl_down(kraw.z, 16, 64);
        a1.u[3] = __shfl_down(kraw.w, 16, 64);
        if (kq == 0) {
            a0.u4 = kraw;
        } else {
            a0.u4 = make_uint4(0, 0, 0, 0);
            a1.u4 = make_uint4(0, 0, 0, 0);
        }
        const f32x4 zz = {0.f, 0.f, 0.f, 0.f};
        f32x4 s0 = __builtin_amdgcn_mfma_f32_16x16x32_bf16(a0.s8, Bq, zz, 0, 0, 0);
        f32x4 s1 = __builtin_amdgcn_mfma_f32_16x16x32_bf16(a1.s8, Bq, zz, 0, 0, 0);

        // V -> Bt[slab]: lane owns column d=l, j = 8wv..8wv+7
        {
            Pack pv;
#pragma unroll
            for (int qv = 0; qv < 8; ++qv) pv.us[qv] = f2bf(vf[qv]);
            *(uint4*)&Bt[slab][l * 40 + 8 * wv] = pv.u4;
        }
        // normalizer (raw S, consistent with numerator) + masked-S store
        {
            float4 cm0 = *(const float4*)&cm_s[j0 + 4 * kq];
            float4 cm1 = *(const float4*)&cm_s[j0 + 16 + 4 * kq];
            nacc += cm0.x * s0[0] + cm0.y * s0[1] + cm0.z * s0[2] + cm0.w * s0[3]
                  + cm1.x * s1[0] + cm1.y * s1[1] + cm1.z * s1[2] + cm1.w * s1[3];
            Pack ps;
            ps.us[0] = f2bf(s0[0] * mv0.x);
            ps.us[1] = f2bf(s0[1] * mv0.y);
            ps.us[2] = f2bf(s0[2] * mv0.z);
            ps.us[3] = f2bf(s0[3] * mv0.w);
            ps.us[4] = f2bf(s1[0] * mv1.x);
            ps.us[5] = f2bf(s1[1] * mv1.y);
            ps.us[6] = f2bf(s1[2] * mv1.z);
            ps.us[7] = f2bf(s1[3] * mv1.w);
            *(uint2*)&SpW[c15 * 40 + 4 * kq] = ps.u2[0];        // j-slots 4kq..+3
            *(uint2*)&SpW[c15 * 40 + 16 + 4 * kq] = ps.u2[1];   // j-slots 16+4kq..+3
        }
        // prefetch next tile (last iter: reload tile 0, discarded)
        {
            const int jn = (jt < 17) ? j0 + 32 : 0;
#pragma unroll
            for (int qv = 0; qv < 8; ++qv) vf[qv] = vb[(size_t)(jn + 8 * wv + qv) * (H_ * D_)];
            mv0 = *(const float4*)(maskbase + jn + 4 * kq);
            mv1 = *(const float4*)(maskbase + jn + 16 + 4 * kq);
            if (kq < 2) kraw = *(const uint4*)(kpb + (size_t)(jn + 16 * kq + c15) * 8);
        }
        __syncthreads();  // Bt[slab] ready (Sp is wave-private; dbuf protects reuse)

        // phase B: A = S[i][j 0..31], B = V[j][d]
        {
            short8 As = *(const short8*)&SpW[c15 * 40 + kq * 8];
            short8 B0 = *(const short8*)&Bt[slab][c15 * 40 + kq * 8];
            short8 B1 = *(const short8*)&Bt[slab][(16 + c15) * 40 + kq * 8];
            short8 B2 = *(const short8*)&Bt[slab][(32 + c15) * 40 + kq * 8];
            short8 B3 = *(const short8*)&Bt[slab][(48 + c15) * 40 + kq * 8];
            acc0 = __builtin_amdgcn_mfma_f32_16x16x32_bf16(As, B0, acc0, 0, 0, 0);
            acc1 = __builtin_amdgcn_mfma_f32_16x16x32_bf16(As, B1, acc1, 0, 0, 0);
            acc2 = __builtin_amdgcn_mfma_f32_16x16x32_bf16(As, B2, acc2, 0, 0, 0);
            acc3 = __builtin_amdgcn_mfma_f32_16x16x32_bf16(As, B3, acc3, 0, 0, 0);
        }
    }

    // normalizer: nacc at lane (c15,kq) is partial for i = i0+16wv+c15; reduce over kq
    nacc += __shfl_xor(nacc, 16, 64);
    nacc += __shfl_xor(nacc, 32, 64);
    // epilogue rows are i = i0+16wv+4kq+r -> fetch denom from lane 4kq+r
    float iv[4];
#pragma unroll
    for (int r = 0; r < 4; ++r) iv[r] = 1.0f / __shfl(nacc, 4 * kq + r, 64);

    float* ob = out + (((size_t)b * L_ + i0 + 16 * wv + 4 * kq) * H_ + h) * D_ + c15;
    const f32x4 aa[4] = {acc0, acc1, acc2, acc3};
#pragma unroll
    for (int di = 0; di < 4; ++di)
#pragma unroll
        for (int r = 0; r < 4; ++r)
            ob[(size_t)r * (H_ * D_) + 16 * di] = aa[di][r] * iv[r];
}

extern "C" void kernel_launch(void* const* d_in, const int* in_sizes, int n_in,
                              void* d_out, int out_size, void* d_ws, size_t ws_size,
                              hipStream_t stream) {
    const float* q    = (const float*)d_in[0];
    const float* k    = (const float*)d_in[1];
    const float* v    = (const float*)d_in[2];
    const float* proj = (const float*)d_in[3];
    const float* mask = (const float*)d_in[4];
    float* out = (float*)d_out;

    float* ws = (float*)d_ws;
    float* cmask = ws;
    unsigned short* qp_w = (unsigned short*)(ws + WS_QP_OFF);
    unsigned short* kp_w = qp_w + QP_ELEMS;

    feat_kernel<<<dim3(L_ / 32, H_, B_), 256, 0, stream>>>(q, k, proj, mask, qp_w, kp_w, cmask);
    attn_kernel<<<1728, 256, 0, stream>>>(v, mask, qp_w, kp_w, cmask, out);
}

// Round 5
// 181.599 us; speedup vs baseline: 2.0897x; 1.0065x over previous
//
#include <hip/hip_runtime.h>
#include <hip/hip_bf16.h>

// MaskedAttention: performer-style relu-feature attention with RPE mask.
// out[b,i,h,:] = (sum_j mask[h,i,j]*(q'[i].k'[j]) * v[j,:]) / (sum_j cmask[h,j]*(q'[i].k'[j]))
// cmask[h,j] = sum_i mask[h,i,j].
// R5: TJ=64 (9 barriers), swizzled cms (b32 broadcast - b128 same-addr bcast is NOT free,
// it was the whole 3.48M conflict count in R4), hw packed bf16 cvt.

#define B_ 16
#define L_ 576
#define H_ 12
#define D_ 64
#define M_ 8
#define NUM_STAB 1e-3f
#define RATIO 0.35355339059327373f  // 1/sqrt(M)

typedef __attribute__((ext_vector_type(8))) short short8;
typedef __attribute__((ext_vector_type(4))) float f32x4;

union Pack {
    uint4 u4;
    short8 s8;
    uint2 u2[2];
    unsigned u[4];
    unsigned short us[8];
};

__device__ inline unsigned short f2bf(float x) {  // RNE fp32 -> bf16 bits (feat kernel)
    union { float f; unsigned u; } a; a.f = x;
    unsigned r = (a.u + 0x7FFFu + ((a.u >> 16) & 1u)) >> 16;
    return (unsigned short)r;
}
__device__ inline unsigned pk2(float lo, float hi) {  // v_cvt_pk_bf16_f32 (RNE)
    __hip_bfloat162 h = __float22bfloat162_rn(make_float2(lo, hi));
    union { __hip_bfloat162 b; unsigned u; } c; c.b = h;
    return c.u;
}

// ws layout: cmask H*L floats, then qp/kp as bf16 [B,H,L,M]
#define WS_QP_OFF (H_ * L_)
#define QP_ELEMS  ((size_t)B_ * H_ * L_ * M_)

// ---------------- kernel 1: features (bf16 out) + fused cmask col-sums ----------------
__global__ __launch_bounds__(256) void feat_kernel(const float* __restrict__ q,
                                                   const float* __restrict__ k,
                                                   const float* __restrict__ proj,
                                                   const float* __restrict__ mask,
                                                   unsigned short* __restrict__ qp,
                                                   unsigned short* __restrict__ kp,
                                                   float* __restrict__ cmask) {
    __shared__ float cred[4][16];
    const int lc = blockIdx.x, h = blockIdx.y, b = blockIdx.z, t = threadIdx.x;
    const int wv = t >> 6, l = t & 63, r8 = l >> 3, c8 = l & 7;
    const int row = lc * 32 + wv * 8 + r8;

    float4 pj0[8], pj1[8];
#pragma unroll
    for (int m = 0; m < 8; ++m) {
        pj0[m] = *(const float4*)(proj + m * 64 + c8 * 8);
        pj1[m] = *(const float4*)(proj + m * 64 + c8 * 8 + 4);
    }

#pragma unroll
    for (int s = 0; s < 2; ++s) {
        const float* src = s ? k : q;
        unsigned short* dst = s ? kp : qp;
        const float* xp = src + (((size_t)b * L_ + row) * H_ + h) * D_ + c8 * 8;
        float4 x0 = *(const float4*)xp;
        float4 x1 = *(const float4*)(xp + 4);
        x0.x *= RATIO; x0.y *= RATIO; x0.z *= RATIO; x0.w *= RATIO;
        x1.x *= RATIO; x1.y *= RATIO; x1.z *= RATIO; x1.w *= RATIO;
        float p[8];
#pragma unroll
        for (int m = 0; m < 8; ++m) {
            p[m] = x0.x * pj0[m].x + x0.y * pj0[m].y + x0.z * pj0[m].z + x0.w * pj0[m].w
                 + x1.x * pj1[m].x + x1.y * pj1[m].y + x1.z * pj1[m].z + x1.w * pj1[m].w;
        }
#pragma unroll
        for (int st = 1; st <= 4; st <<= 1) {
#pragma unroll
            for (int m = 0; m < 8; ++m) p[m] += __shfl_xor(p[m], st, 64);
        }
        float r = p[0];
        r = (c8 == 1) ? p[1] : r;
        r = (c8 == 2) ? p[2] : r;
        r = (c8 == 3) ? p[3] : r;
        r = (c8 == 4) ? p[4] : r;
        r = (c8 == 5) ? p[5] : r;
        r = (c8 == 6) ? p[6] : r;
        r = (c8 == 7) ? p[7] : r;
        r = fmaxf(r, 0.f) + NUM_STAB;
        dst[((size_t)(b * H_ + h) * L_ + row) * 8 + c8] = f2bf(r);
    }

    if (b < 2) {
        const int c = t & 15, rg = t >> 4;
        const int col0 = lc * 32 + b * 16;
        const float* mb = mask + (size_t)h * L_ * L_ + col0 + c;
        float a = 0.f;
#pragma unroll 4
        for (int k2 = 0; k2 < 36; ++k2) a += mb[(size_t)(rg + 16 * k2) * L_];
        a += __shfl_xor(a, 16, 64);
        a += __shfl_xor(a, 32, 64);
        if ((l >> 4) == 0) cred[wv][c] = a;
        __syncthreads();
        if (t < 16) cmask[h * L_ + col0 + t] = cred[0][t] + cred[1][t] + cred[2][t] + cred[3][t];
    }
}

// ---------------- kernel 2: main attention (pure bf16 MFMA, TJ=64) ----------------
// grid 1728 (XCD-swizzled), block 256 (4 waves). Per block: 64 i x 64 d; 9 j-tiles of 64.
// Phase A: 4 subtiles of 16 j via 16x16x32 MFMA (m-features in K slots 0..7).
// Sp wave-private [16 i][72 j-slots]; Bt [64 d][72 j-slots] double-buffered.
// ONE barrier per jt64 (slab argument: Bt[1-slab] writers can only race with
// phase B(jt) readers of Bt[slab] - disjoint).
__global__ __launch_bounds__(256, 4) void attn_kernel(const float* __restrict__ v,
                                                      const float* __restrict__ mask,
                                                      const unsigned short* __restrict__ qp,
                                                      const unsigned short* __restrict__ kp,
                                                      const float* __restrict__ cmask,
                                                      float* __restrict__ out) {
    __shared__ __align__(16) unsigned short Sp[4 * 16 * 72];   // 9216 B, per-wave chunks
    __shared__ __align__(16) unsigned short Bt[2][64 * 72];    // 18432 B
    __shared__ float cms[576];                                 // swizzled [p=16][jt=9][kq=4]

    const int t = threadIdx.x;
    int id = blockIdx.x;
    const int bhi = id & 7; id >>= 3;
    const int blo = id & 1; id >>= 1;
    const int it = id % 9, h = id / 9;
    const int b = bhi * 2 + blo;
    const int i0 = it * 64;

    const int wv = t >> 6, l = t & 63, c15 = l & 15, kq = l >> 4;

    // swizzled cms staging: cms[p*36 + jt*4 + kq] = cmask[h, jt*64 + 16*(p>>2) + 4*kq + (p&3)]
    {
        const float* cmg = cmask + h * L_;
#pragma unroll
        for (int rep = 0; rep < 3; ++rep) {
            int idx = t + rep * 256;
            if (idx < 576) {
                int p = idx / 36, rem = idx - p * 36;
                int jt9 = rem >> 2, kqi = rem & 3;
                int j = jt9 * 64 + ((p >> 2) << 4) + 4 * kqi + (p & 3);
                cms[idx] = cmg[j];
            }
        }
    }

    const float* maskbase = mask + (size_t)h * L_ * L_ + (size_t)(i0 + 16 * wv + c15) * L_;
    const unsigned short* kpb = kp + (size_t)(b * H_ + h) * L_ * 8;
    const float* vb = v + ((size_t)b * L_ * H_ + h) * D_ + l;

    // loop-invariant Q' B-fragment (kq==0 lanes hold Q'[i0+16wv+c15][m0..7])
    short8 Bq;
    {
        Pack pk; pk.u4 = make_uint4(0, 0, 0, 0);
        if (kq == 0) {
            const unsigned short* qpb = qp + ((size_t)(b * H_ + h) * L_ + i0 + 16 * wv + c15) * 8;
            pk.u4 = *(const uint4*)qpb;
        }
        Bq = pk.s8;
    }

    unsigned short* SpW = Sp + wv * 16 * 72;

    f32x4 acc0 = {0.f, 0.f, 0.f, 0.f}, acc1 = acc0, acc2 = acc0, acc3 = acc0;
    float nacc = 0.f;

    // prefetch tile 0
    float vf[16];
    float4 mv[4];
    uint4 kraw0 = make_uint4(0, 0, 0, 0), kraw1 = kraw0;
    {
#pragma unroll
        for (int qv = 0; qv < 16; ++qv) vf[qv] = vb[(size_t)(16 * wv + qv) * (H_ * D_)];
#pragma unroll
        for (int T = 0; T < 4; ++T) mv[T] = *(const float4*)(maskbase + 16 * T + 4 * kq);
        if (kq < 2) {
            kraw0 = *(const uint4*)(kpb + (size_t)(16 * kq + c15) * 8);
            kraw1 = *(const uint4*)(kpb + (size_t)(32 + 16 * kq + c15) * 8);
        }
    }

    __syncthreads();  // cms ready

    for (int jt = 0; jt < 9; ++jt) {
        const int j0 = jt * 64;
        const int slab = jt & 1;

        // ---- phase A: 4 subtiles of 16 j ----
        f32x4 s[4];
        const f32x4 zz = {0.f, 0.f, 0.f, 0.f};
#pragma unroll
        for (int hh = 0; hh < 2; ++hh) {
            uint4 kr = hh ? kraw1 : kraw0;
            Pack a0, a1;
            a1.u[0] = __shfl_down(kr.x, 16, 64);
            a1.u[1] = __shfl_down(kr.y, 16, 64);
            a1.u[2] = __shfl_down(kr.z, 16, 64);
            a1.u[3] = __shfl_down(kr.w, 16, 64);
            if (kq == 0) {
                a0.u4 = kr;
            } else {
                a0.u4 = make_uint4(0, 0, 0, 0);
                a1.u4 = make_uint4(0, 0, 0, 0);
            }
            s[2 * hh]     = __builtin_amdgcn_mfma_f32_16x16x32_bf16(a0.s8, Bq, zz, 0, 0, 0);
            s[2 * hh + 1] = __builtin_amdgcn_mfma_f32_16x16x32_bf16(a1.s8, Bq, zz, 0, 0, 0);
        }

        // ---- V -> Bt[slab] (hw packed cvt) ----
        {
            Pack p0, p1;
#pragma unroll
            for (int qv = 0; qv < 4; ++qv) p0.u[qv] = pk2(vf[2 * qv], vf[2 * qv + 1]);
#pragma unroll
            for (int qv = 0; qv < 4; ++qv) p1.u[qv] = pk2(vf[8 + 2 * qv], vf[9 + 2 * qv]);
            *(uint4*)&Bt[slab][l * 72 + 16 * wv] = p0.u4;
            *(uint4*)&Bt[slab][l * 72 + 16 * wv + 8] = p1.u4;
        }

        // ---- normalizer (raw S x swizzled cms, b32 broadcasts) + masked-S store ----
#pragma unroll
        for (int T = 0; T < 4; ++T) {
            const float* cp = &cms[(T * 4) * 36 + jt * 4 + kq];
            float c0 = cp[0], c1 = cp[36], c2 = cp[72], c3 = cp[108];
            nacc += c0 * s[T][0] + c1 * s[T][1] + c2 * s[T][2] + c3 * s[T][3];
            float4 m4 = mv[T];
            uint2 st2;
            st2.x = pk2(s[T][0] * m4.x, s[T][1] * m4.y);
            st2.y = pk2(s[T][2] * m4.z, s[T][3] * m4.w);
            *(uint2*)&SpW[c15 * 72 + 16 * T + 4 * kq] = st2;
        }

        // ---- prefetch next tile ----
        {
            const int jn = (jt < 8) ? j0 + 64 : 0;
#pragma unroll
            for (int qv = 0; qv < 16; ++qv) vf[qv] = vb[(size_t)(jn + 16 * wv + qv) * (H_ * D_)];
#pragma unroll
            for (int T = 0; T < 4; ++T) mv[T] = *(const float4*)(maskbase + jn + 16 * T + 4 * kq);
            if (kq < 2) {
                kraw0 = *(const uint4*)(kpb + (size_t)(jn + 16 * kq + c15) * 8);
                kraw1 = *(const uint4*)(kpb + (size_t)(jn + 32 + 16 * kq + c15) * 8);
            }
        }

        __syncthreads();  // Bt[slab] + Sp ready

        // ---- phase B: O += S.V over K=64 (2 chunks) ----
        {
            short8 As0 = *(const short8*)&SpW[c15 * 72 + kq * 8];
            short8 As1 = *(const short8*)&SpW[c15 * 72 + 32 + kq * 8];
#pragma unroll
            for (int di = 0; di < 4; ++di) {
                const unsigned short* bp = &Bt[slab][(16 * di + c15) * 72 + kq * 8];
                short8 B0 = *(const short8*)bp;
                short8 B1 = *(const short8*)(bp + 32);
                f32x4* ap = (di == 0) ? &acc0 : (di == 1) ? &acc1 : (di == 2) ? &acc2 : &acc3;
                *ap = __builtin_amdgcn_mfma_f32_16x16x32_bf16(As0, B0, *ap, 0, 0, 0);
                *ap = __builtin_amdgcn_mfma_f32_16x16x32_bf16(As1, B1, *ap, 0, 0, 0);
            }
        }
    }

    // normalizer reduce over kq-copies
    nacc += __shfl_xor(nacc, 16, 64);
    nacc += __shfl_xor(nacc, 32, 64);
    float iv[4];
#pragma unroll
    for (int r = 0; r < 4; ++r) iv[r] = 1.0f / __shfl(nacc, 4 * kq + r, 64);

    float* ob = out + (((size_t)b * L_ + i0 + 16 * wv + 4 * kq) * H_ + h) * D_ + c15;
    const f32x4 aa[4] = {acc0, acc1, acc2, acc3};
#pragma unroll
    for (int di = 0; di < 4; ++di)
#pragma unroll
        for (int r = 0; r < 4; ++r)
            ob[(size_t)r * (H_ * D_) + 16 * di] = aa[di][r] * iv[r];
}

extern "C" void kernel_launch(void* const* d_in, const int* in_sizes, int n_in,
                              void* d_out, int out_size, void* d_ws, size_t ws_size,
                              hipStream_t stream) {
    const float* q    = (const float*)d_in[0];
    const float* k    = (const float*)d_in[1];
    const float* v    = (const float*)d_in[2];
    const float* proj = (const float*)d_in[3];
    const float* mask = (const float*)d_in[4];
    float* out = (float*)d_out;

    float* ws = (float*)d_ws;
    float* cmask = ws;
    unsigned short* qp_w = (unsigned short*)(ws + WS_QP_OFF);
    unsigned short* kp_w = qp_w + QP_ELEMS;

    feat_kernel<<<dim3(L_ / 32, H_, B_), 256, 0, stream>>>(q, k, proj, mask, qp_w, kp_w, cmask);
    attn_kernel<<<1728, 256, 0, stream>>>(v, mask, qp_w, kp_w, cmask, out);
}